// Round 3
// baseline (327.485 us; speedup 1.0000x reference)
//
#include <hip/hip_runtime.h>
#include <stdint.h>

#define SEQ 2048
#define BS 2
#define EMB 1024
#define NH 16
#define HD 64
#define F3 3072

using f32x4 = __attribute__((ext_vector_type(4))) float;
using bf16x8 = __attribute__((ext_vector_type(8))) short;

__device__ __forceinline__ unsigned short f2bf(float f) {
    union { float f; uint32_t u; } v; v.f = f;
    uint32_t u = v.u;
    u = u + 0x7FFFu + ((u >> 16) & 1u);   // RNE
    return (unsigned short)(u >> 16);
}

#define GLOAD_LDS16(g, l) \
    __builtin_amdgcn_global_load_lds((const __attribute__((address_space(1))) void*)(g), \
                                     (__attribute__((address_space(3))) void*)(l), 16, 0, 0)

// ---------------- fp32 -> bf16 conversion ----------------
__global__ void cvt_kernel(const float* __restrict__ in, unsigned short* __restrict__ out, int n4) {
    int i = blockIdx.x * blockDim.x + threadIdx.x;
    if (i < n4) {
        f32x4 v = reinterpret_cast<const f32x4*>(in)[i];
        ushort4 o;
        o.x = f2bf(v.x); o.y = f2bf(v.y); o.z = f2bf(v.z); o.w = f2bf(v.w);
        reinterpret_cast<ushort4*>(out)[i] = o;
    }
}

// ---------------- GEMM: C[M,N] = A[M,K] @ B[N,K]^T (bf16 in, bf16 or f32 out) ----------------
template <bool BF16OUT>
__global__ __launch_bounds__(256) void gemm_bt(
    const unsigned short* __restrict__ A,
    const unsigned short* __restrict__ B,
    void* __restrict__ Cv,
    int M, int N, int K)
{
    __shared__ unsigned short As[128 * 32];
    __shared__ unsigned short Bs[128 * 32];
    const int tid  = threadIdx.x;
    const int wave = tid >> 6, lane = tid & 63;
    const int wr = wave >> 1, wc = wave & 1;
    const int row0 = blockIdx.y * 128, col0 = blockIdx.x * 128;

    f32x4 acc[4][4] = {};

    const int srow = wave * 16 + (lane >> 2);   // staging row within 64-row group
    const int scol = (lane & 3) * 8;

    const unsigned short* gA = A + (size_t)(row0 + srow) * K + scol;
    const unsigned short* gB = B + (size_t)(col0 + srow) * K + scol;
    unsigned short* lA = As + wave * 16 * 32;   // wave-uniform LDS base
    unsigned short* lB = Bs + wave * 16 * 32;

    for (int kb = 0; kb < K; kb += 32) {
        __syncthreads();
        GLOAD_LDS16(gA + kb,                    lA);
        GLOAD_LDS16(gA + (size_t)64 * K + kb,   lA + 64 * 32);
        GLOAD_LDS16(gB + kb,                    lB);
        GLOAD_LDS16(gB + (size_t)64 * K + kb,   lB + 64 * 32);
        asm volatile("s_waitcnt vmcnt(0)" ::: "memory");
        __syncthreads();

        bf16x8 af[4], bfr[4];
#pragma unroll
        for (int mi = 0; mi < 4; mi++)
            af[mi] = *reinterpret_cast<const bf16x8*>(As + (wr * 64 + mi * 16 + (lane & 15)) * 32 + (lane >> 4) * 8);
#pragma unroll
        for (int ni = 0; ni < 4; ni++)
            bfr[ni] = *reinterpret_cast<const bf16x8*>(Bs + (wc * 64 + ni * 16 + (lane & 15)) * 32 + (lane >> 4) * 8);
#pragma unroll
        for (int mi = 0; mi < 4; mi++)
#pragma unroll
            for (int ni = 0; ni < 4; ni++)
                acc[mi][ni] = __builtin_amdgcn_mfma_f32_16x16x32_bf16(af[mi], bfr[ni], acc[mi][ni], 0, 0, 0);
    }

#pragma unroll
    for (int mi = 0; mi < 4; mi++)
#pragma unroll
        for (int ni = 0; ni < 4; ni++)
#pragma unroll
            for (int r = 0; r < 4; r++) {
                int row = row0 + wr * 64 + mi * 16 + (lane >> 4) * 4 + r;
                int col = col0 + wc * 64 + ni * 16 + (lane & 15);
                float v = acc[mi][ni][r];
                if constexpr (BF16OUT)
                    ((unsigned short*)Cv)[(size_t)row * N + col] = f2bf(v);
                else
                    ((float*)Cv)[(size_t)row * N + col] = v;
            }
}

// ---------------- causal flash attention ----------------
// qkv: [BS][SEQ][3*EMB] bf16 (q|k|v each EMB, head h at h*HD)
// ao : [BS][SEQ][EMB]   bf16
__global__ __launch_bounds__(256) void attn_kernel(
    const unsigned short* __restrict__ qkv,
    unsigned short* __restrict__ ao)
{
    const int qb = blockIdx.x;          // q-block of 128 rows
    const int bh = blockIdx.y;          // b*NH + h
    const int b = bh >> 4, h = bh & 15;
    const int tid = threadIdx.x, wave = tid >> 6, lane = tid & 63;

    __shared__ unsigned short Ks[64 * 64];      // [kpos][d]  (XOR-swizzled rows)
    __shared__ unsigned short Vs[64 * 64];      // [d][kpos]  (transposed, swizzled)
    __shared__ unsigned short Ps[4][32 * 64];   // per-wave P tile [q][kpos] (swizzled)

    const size_t base = (size_t)b * SEQ * F3;
    const int qrow0 = qb * 128 + wave * 32;

    // Q fragments in registers: [mi][kstep]
    bf16x8 qf[2][2];
#pragma unroll
    for (int mi = 0; mi < 2; mi++)
#pragma unroll
        for (int s = 0; s < 2; s++) {
            int row = qrow0 + mi * 16 + (lane & 15);
            int d   = s * 32 + (lane >> 4) * 8;
            qf[mi][s] = *reinterpret_cast<const bf16x8*>(qkv + base + (size_t)row * F3 + h * HD + d);
        }

    f32x4 po[2][4] = {};
    float mR[2][4], lR[2][4];
#pragma unroll
    for (int mi = 0; mi < 2; mi++)
#pragma unroll
        for (int r = 0; r < 4; r++) { mR[mi][r] = -1e30f; lR[mi][r] = 0.f; }

    const int ktiles = (qb * 128 + 128) >> 6;
    const int srow = tid >> 3;   // 0..31
    const int sch  = tid & 7;    // 16B chunk in 128B row

    for (int kt = 0; kt < ktiles; kt++) {
        const int kbase = kt * 64;
        __syncthreads();
        // stage K tile [64][64]
#pragma unroll
        for (int i = 0; i < 2; i++) {
            int row = i * 32 + srow;
            bf16x8 kv = *reinterpret_cast<const bf16x8*>(qkv + base + (size_t)(kbase + row) * F3 + EMB + h * HD + sch * 8);
            int off = (row * 128 + sch * 16) ^ ((row & 7) << 4);
            *reinterpret_cast<bf16x8*>((char*)Ks + off) = kv;
        }
        // stage V transposed: Vs[d][kpos]
#pragma unroll
        for (int i = 0; i < 2; i++) {
            int kp = i * 32 + srow;
            bf16x8 vv = *reinterpret_cast<const bf16x8*>(qkv + base + (size_t)(kbase + kp) * F3 + 2 * EMB + h * HD + sch * 8);
#pragma unroll
            for (int j = 0; j < 8; j++) {
                int d = sch * 8 + j;
                int off = (d * 128 + kp * 2) ^ ((d & 7) << 4);
                *reinterpret_cast<unsigned short*>((char*)Vs + off) = (unsigned short)vv[j];
            }
        }
        __syncthreads();

        const bool active = kbase <= qrow0 + 31;   // any unmasked entry for this wave?
        if (active) {
            // S = Q @ K^T   [32 q][64 k]
            f32x4 sAcc[2][4] = {};
#pragma unroll
            for (int dstep = 0; dstep < 2; dstep++) {
                bf16x8 kf[4];
#pragma unroll
                for (int ni = 0; ni < 4; ni++) {
                    int row = ni * 16 + (lane & 15);
                    int off = (row * 128 + dstep * 64 + (lane >> 4) * 16) ^ ((row & 7) << 4);
                    kf[ni] = *reinterpret_cast<const bf16x8*>((char*)Ks + off);
                }
#pragma unroll
                for (int mi = 0; mi < 2; mi++)
#pragma unroll
                    for (int ni = 0; ni < 4; ni++)
                        sAcc[mi][ni] = __builtin_amdgcn_mfma_f32_16x16x32_bf16(qf[mi][dstep], kf[ni], sAcc[mi][ni], 0, 0, 0);
            }

            const bool needmask = (kbase + 63) > qrow0;
            // online softmax (C-layout: col=lane&15, row=(lane>>4)*4+reg)
#pragma unroll
            for (int mi = 0; mi < 2; mi++) {
#pragma unroll
                for (int r = 0; r < 4; r++) {
                    int q = qrow0 + mi * 16 + ((lane >> 4) << 2) + r;
                    float mx = -1e30f;
#pragma unroll
                    for (int ni = 0; ni < 4; ni++) {
                        float v = sAcc[mi][ni][r] * 0.125f;
                        if (needmask) {
                            int k = kbase + ni * 16 + (lane & 15);
                            if (k > q) v = -1e30f;
                        }
                        sAcc[mi][ni][r] = v;
                        mx = fmaxf(mx, v);
                    }
                    mx = fmaxf(mx, __shfl_xor(mx, 1));
                    mx = fmaxf(mx, __shfl_xor(mx, 2));
                    mx = fmaxf(mx, __shfl_xor(mx, 4));
                    mx = fmaxf(mx, __shfl_xor(mx, 8));
                    float mn = fmaxf(mR[mi][r], mx);
                    float alpha = exp2f((mR[mi][r] - mn) * 1.44269504f);
                    mR[mi][r] = mn;
                    float rs = 0.f;
#pragma unroll
                    for (int ni = 0; ni < 4; ni++) {
                        float p = exp2f((sAcc[mi][ni][r] - mn) * 1.44269504f);
                        sAcc[mi][ni][r] = p;
                        rs += p;
                    }
                    rs += __shfl_xor(rs, 1);
                    rs += __shfl_xor(rs, 2);
                    rs += __shfl_xor(rs, 4);
                    rs += __shfl_xor(rs, 8);
                    lR[mi][r] = lR[mi][r] * alpha + rs;
#pragma unroll
                    for (int ni = 0; ni < 4; ni++) po[mi][ni][r] *= alpha;
                }
            }

            // P -> wave-private LDS (bf16, swizzled), then PV
            unsigned short* Pw = Ps[wave];
#pragma unroll
            for (int mi = 0; mi < 2; mi++)
#pragma unroll
                for (int ni = 0; ni < 4; ni++)
#pragma unroll
                    for (int r = 0; r < 4; r++) {
                        int row = mi * 16 + (lane >> 4) * 4 + r;
                        int col = ni * 16 + (lane & 15);
                        int off = (row * 128 + col * 2) ^ ((row & 7) << 4);
                        *reinterpret_cast<unsigned short*>((char*)Pw + off) = f2bf(sAcc[mi][ni][r]);
                    }
#pragma unroll
            for (int s2 = 0; s2 < 2; s2++) {
                bf16x8 pa[2], vb[4];
#pragma unroll
                for (int mi = 0; mi < 2; mi++) {
                    int row = mi * 16 + (lane & 15);
                    int off = (row * 128 + s2 * 64 + (lane >> 4) * 16) ^ ((row & 7) << 4);
                    pa[mi] = *reinterpret_cast<const bf16x8*>((char*)Pw + off);
                }
#pragma unroll
                for (int ni = 0; ni < 4; ni++) {
                    int n = ni * 16 + (lane & 15);
                    int off = (n * 128 + s2 * 64 + (lane >> 4) * 16) ^ ((n & 7) << 4);
                    vb[ni] = *reinterpret_cast<const bf16x8*>((char*)Vs + off);
                }
#pragma unroll
                for (int mi = 0; mi < 2; mi++)
#pragma unroll
                    for (int ni = 0; ni < 4; ni++)
                        po[mi][ni] = __builtin_amdgcn_mfma_f32_16x16x32_bf16(pa[mi], vb[ni], po[mi][ni], 0, 0, 0);
            }
        }
    }

    // epilogue: ao[b, q, h*HD + d] = po / l
#pragma unroll
    for (int mi = 0; mi < 2; mi++)
#pragma unroll
        for (int r = 0; r < 4; r++) {
            float inv = 1.0f / lR[mi][r];
            int row = qrow0 + mi * 16 + (lane >> 4) * 4 + r;
#pragma unroll
            for (int ni = 0; ni < 4; ni++) {
                int d = ni * 16 + (lane & 15);
                ao[(size_t)(b * SEQ + row) * EMB + h * HD + d] = f2bf(po[mi][ni][r] * inv);
            }
        }
}

// ---------------- launch ----------------
extern "C" void kernel_launch(void* const* d_in, const int* in_sizes, int n_in,
                              void* d_out, int out_size, void* d_ws, size_t ws_size,
                              hipStream_t stream)
{
    const float* x    = (const float*)d_in[0];
    const float* Win  = (const float*)d_in[1];
    const float* Wout = (const float*)d_in[2];
    float* out = (float*)d_out;

    char* ws = (char*)d_ws;
    unsigned short* xb    = (unsigned short*)(ws);                  //  8 MB
    unsigned short* winb  = (unsigned short*)(ws + (8u  << 20));    //  6 MB
    unsigned short* woutb = (unsigned short*)(ws + (14u << 20));    //  2 MB
    unsigned short* qkvb  = (unsigned short*)(ws + (16u << 20));    // 24 MB
    unsigned short* aob   = (unsigned short*)(ws + (40u << 20));    //  8 MB

    const int nx    = BS * SEQ * EMB;   // 4194304
    const int nwin  = F3 * EMB;         // 3145728
    const int nwout = EMB * EMB;        // 1048576

    cvt_kernel<<<nx    / 4 / 256, 256, 0, stream>>>(x,    xb,    nx / 4);
    cvt_kernel<<<nwin  / 4 / 256, 256, 0, stream>>>(Win,  winb,  nwin / 4);
    cvt_kernel<<<nwout / 4 / 256, 256, 0, stream>>>(Wout, woutb, nwout / 4);

    dim3 g1(F3 / 128, BS * SEQ / 128);   // (24, 32)
    gemm_bt<true><<<g1, 256, 0, stream>>>(xb, winb, (void*)qkvb, BS * SEQ, F3, EMB);

    dim3 g2(SEQ / 128, BS * NH);         // (16, 32)
    attn_kernel<<<g2, 256, 0, stream>>>(qkvb, aob);

    dim3 g3(EMB / 128, BS * SEQ / 128);  // (8, 32)
    gemm_bt<false><<<g3, 256, 0, stream>>>(aob, woutb, (void*)out, BS * SEQ, EMB, EMB);
}

// Round 5
// 236.536 us; speedup vs baseline: 1.3845x; 1.3845x over previous
//
#include <hip/hip_runtime.h>
#include <stdint.h>

#define SEQ 2048
#define BS 2
#define EMB 1024
#define NH 16
#define HD 64
#define F3 3072

using f32x4 = __attribute__((ext_vector_type(4))) float;
using bf16x8 = __attribute__((ext_vector_type(8))) short;

__device__ __forceinline__ unsigned short f2bf(float f) {
    union { float f; uint32_t u; } v; v.f = f;
    uint32_t u = v.u;
    u = u + 0x7FFFu + ((u >> 16) & 1u);   // RNE
    return (unsigned short)(u >> 16);
}

#define GLOAD_LDS16(g, l) \
    __builtin_amdgcn_global_load_lds((const __attribute__((address_space(1))) void*)(g), \
                                     (__attribute__((address_space(3))) void*)(l), 16, 0, 0)

// ---------------- fp32 -> bf16 conversion ----------------
__global__ void cvt_kernel(const float* __restrict__ in, unsigned short* __restrict__ out, int n4) {
    int i = blockIdx.x * blockDim.x + threadIdx.x;
    if (i < n4) {
        f32x4 v = reinterpret_cast<const f32x4*>(in)[i];
        ushort4 o;
        o.x = f2bf(v.x); o.y = f2bf(v.y); o.z = f2bf(v.z); o.w = f2bf(v.w);
        reinterpret_cast<ushort4*>(out)[i] = o;
    }
}

// ---------------- GEMM: C[M,N] = A[M,K] @ B[N,K]^T (bf16 in, bf16 or f32 out) ----------------
template <bool BF16OUT>
__global__ __launch_bounds__(256) void gemm_bt(
    const unsigned short* __restrict__ A,
    const unsigned short* __restrict__ B,
    void* __restrict__ Cv,
    int M, int N, int K)
{
    __shared__ unsigned short As[128 * 32];
    __shared__ unsigned short Bs[128 * 32];
    const int tid  = threadIdx.x;
    const int wave = tid >> 6, lane = tid & 63;
    const int wr = wave >> 1, wc = wave & 1;
    const int row0 = blockIdx.y * 128, col0 = blockIdx.x * 128;

    f32x4 acc[4][4] = {};

    const int srow = wave * 16 + (lane >> 2);
    const int scol = (lane & 3) * 8;

    const unsigned short* gA = A + (size_t)(row0 + srow) * K + scol;
    const unsigned short* gB = B + (size_t)(col0 + srow) * K + scol;
    unsigned short* lA = As + wave * 16 * 32;
    unsigned short* lB = Bs + wave * 16 * 32;

    for (int kb = 0; kb < K; kb += 32) {
        __syncthreads();
        GLOAD_LDS16(gA + kb,                    lA);
        GLOAD_LDS16(gA + (size_t)64 * K + kb,   lA + 64 * 32);
        GLOAD_LDS16(gB + kb,                    lB);
        GLOAD_LDS16(gB + (size_t)64 * K + kb,   lB + 64 * 32);
        asm volatile("s_waitcnt vmcnt(0)" ::: "memory");
        __syncthreads();

        bf16x8 af[4], bfr[4];
#pragma unroll
        for (int mi = 0; mi < 4; mi++)
            af[mi] = *reinterpret_cast<const bf16x8*>(As + (wr * 64 + mi * 16 + (lane & 15)) * 32 + (lane >> 4) * 8);
#pragma unroll
        for (int ni = 0; ni < 4; ni++)
            bfr[ni] = *reinterpret_cast<const bf16x8*>(Bs + (wc * 64 + ni * 16 + (lane & 15)) * 32 + (lane >> 4) * 8);
#pragma unroll
        for (int mi = 0; mi < 4; mi++)
#pragma unroll
            for (int ni = 0; ni < 4; ni++)
                acc[mi][ni] = __builtin_amdgcn_mfma_f32_16x16x32_bf16(af[mi], bfr[ni], acc[mi][ni], 0, 0, 0);
    }

#pragma unroll
    for (int mi = 0; mi < 4; mi++)
#pragma unroll
        for (int ni = 0; ni < 4; ni++)
#pragma unroll
            for (int r = 0; r < 4; r++) {
                int row = row0 + wr * 64 + mi * 16 + (lane >> 4) * 4 + r;
                int col = col0 + wc * 64 + ni * 16 + (lane & 15);
                float v = acc[mi][ni][r];
                if constexpr (BF16OUT)
                    ((unsigned short*)Cv)[(size_t)row * N + col] = f2bf(v);
                else
                    ((float*)Cv)[(size_t)row * N + col] = v;
            }
}

// ---------------- causal flash attention (swapped-QK^T, in-register softmax) ----------------
// qkv: [BS][SEQ][3*EMB] bf16 ; ao: [BS][SEQ][EMB] bf16
__global__ __launch_bounds__(256) void attn_kernel(
    const unsigned short* __restrict__ qkv,
    unsigned short* __restrict__ ao)
{
    // LPT scheduling: heaviest q-blocks (qb=15) dispatched first
    const int idx = blockIdx.x;
    const int qb = 15 - (idx >> 5);
    const int bh = idx & 31;
    const int b = bh >> 4, h = bh & 15;
    const int tid = threadIdx.x, wave = tid >> 6, lane = tid & 63;
    const int c = lane & 15, g = lane >> 4;

    __shared__ unsigned short Ks[64 * 64];      // [kpos][d]  XOR-swizzled
    __shared__ unsigned short Vs[64 * 64];      // [d][kpos]  transposed, swizzled
    __shared__ unsigned short Ps[4][32 * 64];   // per-wave P [q][k] swizzled

    const size_t base = (size_t)b * SEQ * F3;
    const int qrow0 = qb * 128 + wave * 32;
    const float SC = 0.18033688011f;            // 0.125 * log2(e)

    // Q fragments (B-operand of swapped QK^T): [qt][dstep]
    bf16x8 qf[2][2];
#pragma unroll
    for (int qt = 0; qt < 2; qt++)
#pragma unroll
        for (int s = 0; s < 2; s++) {
            int row = qrow0 + qt * 16 + c;
            int d   = s * 32 + g * 8;
            qf[qt][s] = *reinterpret_cast<const bf16x8*>(qkv + base + (size_t)row * F3 + h * HD + d);
        }

    f32x4 po[2][4] = {};
    float mR[2], lR[2];
    mR[0] = mR[1] = -1e30f; lR[0] = lR[1] = 0.f;

    const int ktiles = (qb * 128 + 128) >> 6;
    const int krow2 = (tid >> 3) * 2;   // V staging: rows krow2, krow2+1
    const int sch  = tid & 7;           // 16B chunk
    const int ksrow = tid >> 3;         // K staging row (0..31), 2 iters

    for (int kt_i = 0; kt_i < ktiles; kt_i++) {
        const int kbase = kt_i * 64;
        __syncthreads();
        // stage K tile [64][64] (swizzled rows)
#pragma unroll
        for (int i = 0; i < 2; i++) {
            int row = i * 32 + ksrow;
            bf16x8 kv = *reinterpret_cast<const bf16x8*>(qkv + base + (size_t)(kbase + row) * F3 + EMB + h * HD + sch * 8);
            int off = (row * 128 + sch * 16) ^ ((row & 7) << 4);
            *reinterpret_cast<bf16x8*>((char*)Ks + off) = kv;
        }
        // stage V transposed: Vs[d][kpos], packed pair-row writes
        {
            bf16x8 vv0 = *reinterpret_cast<const bf16x8*>(qkv + base + (size_t)(kbase + krow2) * F3 + 2 * EMB + h * HD + sch * 8);
            bf16x8 vv1 = *reinterpret_cast<const bf16x8*>(qkv + base + (size_t)(kbase + krow2 + 1) * F3 + 2 * EMB + h * HD + sch * 8);
#pragma unroll
            for (int j = 0; j < 8; j++) {
                int d = sch * 8 + j;
                int off = (d * 128 + krow2 * 2) ^ ((d & 7) << 4);
                ushort2 pr; pr.x = (unsigned short)vv0[j]; pr.y = (unsigned short)vv1[j];
                *reinterpret_cast<ushort2*>((char*)Vs + off) = pr;
            }
        }
        __syncthreads();

        const bool active = kbase <= qrow0 + 31;
        if (active) {
            // S^T = K @ Q^T : st[kt][qt], lane holds q = qt*16+c, k = kbase + kt*16 + g*4 + r
            f32x4 st[4][2] = {};
#pragma unroll
            for (int dstep = 0; dstep < 2; dstep++) {
                bf16x8 kf[4];
#pragma unroll
                for (int kt = 0; kt < 4; kt++) {
                    int row = kt * 16 + c;
                    int off = (row * 128 + dstep * 64 + g * 16) ^ ((row & 7) << 4);
                    kf[kt] = *reinterpret_cast<const bf16x8*>((char*)Ks + off);
                }
#pragma unroll
                for (int kt = 0; kt < 4; kt++)
#pragma unroll
                    for (int qt = 0; qt < 2; qt++)
                        st[kt][qt] = __builtin_amdgcn_mfma_f32_16x16x32_bf16(kf[kt], qf[qt][dstep], st[kt][qt], 0, 0, 0);
            }

            const bool needmask = (kbase + 63) > qrow0;
            float alphav[2];
#pragma unroll
            for (int qt = 0; qt < 2; qt++) {
                const int q = qrow0 + qt * 16 + c;
                float mx = -3.0e38f;
#pragma unroll
                for (int kt = 0; kt < 4; kt++)
#pragma unroll
                    for (int r = 0; r < 4; r++) {
                        float v = st[kt][qt][r];
                        if (needmask) {
                            int k = kbase + kt * 16 + g * 4 + r;
                            if (k > q) v = -3.0e38f;
                        }
                        st[kt][qt][r] = v;
                        mx = fmaxf(mx, v);
                    }
                mx = fmaxf(mx, __shfl_xor(mx, 16));
                mx = fmaxf(mx, __shfl_xor(mx, 32));
                float mn = fmaxf(mR[qt], mx);
                alphav[qt] = exp2f((mR[qt] - mn) * SC);
                mR[qt] = mn;
                float rs = 0.f;
#pragma unroll
                for (int kt = 0; kt < 4; kt++)
#pragma unroll
                    for (int r = 0; r < 4; r++) {
                        float p = exp2f((st[kt][qt][r] - mn) * SC);
                        st[kt][qt][r] = p;
                        rs += p;
                    }
                rs += __shfl_xor(rs, 16);
                rs += __shfl_xor(rs, 32);
                lR[qt] = lR[qt] * alphav[qt] + rs;
            }

            // rescale O accumulator: row r of po = q-row g*4+r -> fetch alpha from lane (g*4+r)
#pragma unroll
            for (int qt = 0; qt < 2; qt++)
#pragma unroll
                for (int r = 0; r < 4; r++) {
                    float ar = __shfl(alphav[qt], (g << 2) + r);
#pragma unroll
                    for (int ni = 0; ni < 4; ni++) po[qt][ni][r] *= ar;
                }

            // P -> wave LDS: packed b64 writes (4 consecutive k per lane)
            unsigned short* Pw = Ps[wave];
#pragma unroll
            for (int qt = 0; qt < 2; qt++) {
                int row = qt * 16 + c;
#pragma unroll
                for (int kt = 0; kt < 4; kt++) {
                    uint32_t lo = (uint32_t)f2bf(st[kt][qt][0]) | ((uint32_t)f2bf(st[kt][qt][1]) << 16);
                    uint32_t hi = (uint32_t)f2bf(st[kt][qt][2]) | ((uint32_t)f2bf(st[kt][qt][3]) << 16);
                    int off = (row * 128 + kt * 32 + g * 8) ^ ((row & 7) << 4);
                    uint2 pk; pk.x = lo; pk.y = hi;
                    *reinterpret_cast<uint2*>((char*)Pw + off) = pk;
                }
            }

            // PV: O[q][d] += P @ V
#pragma unroll
            for (int s2 = 0; s2 < 2; s2++) {
                bf16x8 pa[2], vb[4];
#pragma unroll
                for (int mi = 0; mi < 2; mi++) {
                    int row = mi * 16 + c;
                    int off = (row * 128 + s2 * 64 + g * 16) ^ ((row & 7) << 4);
                    pa[mi] = *reinterpret_cast<const bf16x8*>((char*)Pw + off);
                }
#pragma unroll
                for (int ni = 0; ni < 4; ni++) {
                    int n = ni * 16 + c;
                    int off = (n * 128 + s2 * 64 + g * 16) ^ ((n & 7) << 4);
                    vb[ni] = *reinterpret_cast<const bf16x8*>((char*)Vs + off);
                }
#pragma unroll
                for (int mi = 0; mi < 2; mi++)
#pragma unroll
                    for (int ni = 0; ni < 4; ni++)
                        po[mi][ni] = __builtin_amdgcn_mfma_f32_16x16x32_bf16(pa[mi], vb[ni], po[mi][ni], 0, 0, 0);
            }
        }
    }

    // epilogue
#pragma unroll
    for (int qt = 0; qt < 2; qt++) {
        float invl = 1.0f / lR[qt];
#pragma unroll
        for (int r = 0; r < 4; r++) {
            float iv = __shfl(invl, (g << 2) + r);
            int row = qrow0 + qt * 16 + g * 4 + r;
#pragma unroll
            for (int ni = 0; ni < 4; ni++) {
                int d = ni * 16 + c;
                ao[(size_t)(b * SEQ + row) * EMB + h * HD + d] = f2bf(po[qt][ni][r] * iv);
            }
        }
    }
}

// ---------------- launch ----------------
extern "C" void kernel_launch(void* const* d_in, const int* in_sizes, int n_in,
                              void* d_out, int out_size, void* d_ws, size_t ws_size,
                              hipStream_t stream)
{
    const float* x    = (const float*)d_in[0];
    const float* Win  = (const float*)d_in[1];
    const float* Wout = (const float*)d_in[2];
    float* out = (float*)d_out;

    char* ws = (char*)d_ws;
    unsigned short* xb    = (unsigned short*)(ws);
    unsigned short* winb  = (unsigned short*)(ws + (8u  << 20));
    unsigned short* woutb = (unsigned short*)(ws + (14u << 20));
    unsigned short* qkvb  = (unsigned short*)(ws + (16u << 20));
    unsigned short* aob   = (unsigned short*)(ws + (40u << 20));

    const int nx    = BS * SEQ * EMB;
    const int nwin  = F3 * EMB;
    const int nwout = EMB * EMB;

    cvt_kernel<<<nx    / 4 / 256, 256, 0, stream>>>(x,    xb,    nx / 4);
    cvt_kernel<<<nwin  / 4 / 256, 256, 0, stream>>>(Win,  winb,  nwin / 4);
    cvt_kernel<<<nwout / 4 / 256, 256, 0, stream>>>(Wout, woutb, nwout / 4);

    dim3 g1(F3 / 128, BS * SEQ / 128);
    gemm_bt<true><<<g1, 256, 0, stream>>>(xb, winb, (void*)qkvb, BS * SEQ, F3, EMB);

    attn_kernel<<<dim3(512), 256, 0, stream>>>(qkvb, aob);

    dim3 g3(EMB / 128, BS * SEQ / 128);
    gemm_bt<false><<<g3, 256, 0, stream>>>(aob, woutb, (void*)out, BS * SEQ, EMB, EMB);
}

// Round 7
// 205.871 us; speedup vs baseline: 1.5907x; 1.1490x over previous
//
#include <hip/hip_runtime.h>
#include <stdint.h>

#define SEQ 2048
#define BS 2
#define EMB 1024
#define NH 16
#define HD 64
#define F3 3072

using f32x4 = __attribute__((ext_vector_type(4))) float;
using bf16x8 = __attribute__((ext_vector_type(8))) short;

__device__ __forceinline__ unsigned short f2bf(float f) {
    union { float f; uint32_t u; } v; v.f = f;
    uint32_t u = v.u;
    u = u + 0x7FFFu + ((u >> 16) & 1u);   // RNE
    return (unsigned short)(u >> 16);
}

// v_cvt_pk_bf16_f32: dst = {hi16=cvt(b), lo16=cvt(a)}  (no builtin on gfx950 — T12 recipe)
__device__ __forceinline__ uint32_t pk_bf16(float a, float b) {
    uint32_t r;
    asm("v_cvt_pk_bf16_f32 %0, %1, %2" : "=v"(r) : "v"(a), "v"(b));
    return r;
}

#define GLOAD_LDS16(g, l) \
    __builtin_amdgcn_global_load_lds((const __attribute__((address_space(1))) void*)(g), \
                                     (__attribute__((address_space(3))) void*)(l), 16, 0, 0)

// ---------------- fp32 -> bf16 conversion ----------------
__global__ void cvt_kernel(const float* __restrict__ in, unsigned short* __restrict__ out, int n4) {
    int i = blockIdx.x * blockDim.x + threadIdx.x;
    if (i < n4) {
        f32x4 v = reinterpret_cast<const f32x4*>(in)[i];
        uint2 o;
        o.x = pk_bf16(v.x, v.y);
        o.y = pk_bf16(v.z, v.w);
        reinterpret_cast<uint2*>(out)[i] = o;
    }
}

// ---------------- GEMM: C[M,N] = A[M,K] @ B[N,K]^T, 1D grid + XCD swizzle ----------------
template <bool BF16OUT>
__global__ __launch_bounds__(256) void gemm_bt(
    const unsigned short* __restrict__ A,
    const unsigned short* __restrict__ B,
    void* __restrict__ Cv,
    int M, int N, int K, int nbx)
{
    __shared__ unsigned short As[128 * 32];
    __shared__ unsigned short Bs[128 * 32];
    const int tid  = threadIdx.x;
    const int wave = tid >> 6, lane = tid & 63;
    const int wr = wave >> 1, wc = wave & 1;

    // XCD-aware swizzle: nwg % 8 == 0 guaranteed by launch
    const int nwg = gridDim.x;
    const int s = (blockIdx.x & 7) * (nwg >> 3) + (blockIdx.x >> 3);
    const int bx = s % nbx, by = s / nbx;
    const int row0 = by * 128, col0 = bx * 128;

    f32x4 acc[4][4] = {};

    const int srow = wave * 16 + (lane >> 2);
    const int scol = (lane & 3) * 8;

    const unsigned short* gA = A + (size_t)(row0 + srow) * K + scol;
    const unsigned short* gB = B + (size_t)(col0 + srow) * K + scol;
    unsigned short* lA = As + wave * 16 * 32;
    unsigned short* lB = Bs + wave * 16 * 32;

    for (int kb = 0; kb < K; kb += 32) {
        __syncthreads();
        GLOAD_LDS16(gA + kb,                    lA);
        GLOAD_LDS16(gA + (size_t)64 * K + kb,   lA + 64 * 32);
        GLOAD_LDS16(gB + kb,                    lB);
        GLOAD_LDS16(gB + (size_t)64 * K + kb,   lB + 64 * 32);
        asm volatile("s_waitcnt vmcnt(0)" ::: "memory");
        __syncthreads();

        bf16x8 af[4], bfr[4];
#pragma unroll
        for (int mi = 0; mi < 4; mi++)
            af[mi] = *reinterpret_cast<const bf16x8*>(As + (wr * 64 + mi * 16 + (lane & 15)) * 32 + (lane >> 4) * 8);
#pragma unroll
        for (int ni = 0; ni < 4; ni++)
            bfr[ni] = *reinterpret_cast<const bf16x8*>(Bs + (wc * 64 + ni * 16 + (lane & 15)) * 32 + (lane >> 4) * 8);
#pragma unroll
        for (int mi = 0; mi < 4; mi++)
#pragma unroll
            for (int ni = 0; ni < 4; ni++)
                acc[mi][ni] = __builtin_amdgcn_mfma_f32_16x16x32_bf16(af[mi], bfr[ni], acc[mi][ni], 0, 0, 0);
    }

#pragma unroll
    for (int mi = 0; mi < 4; mi++)
#pragma unroll
        for (int ni = 0; ni < 4; ni++)
#pragma unroll
            for (int r = 0; r < 4; r++) {
                int row = row0 + wr * 64 + mi * 16 + (lane >> 4) * 4 + r;
                int col = col0 + wc * 64 + ni * 16 + (lane & 15);
                float v = acc[mi][ni][r];
                if constexpr (BF16OUT)
                    ((unsigned short*)Cv)[(size_t)row * N + col] = f2bf(v);
                else
                    ((float*)Cv)[(size_t)row * N + col] = v;
            }
}

// ---------------- causal flash attention ----------------
// swapped-QK^T in-reg softmax + reg-prefetch staging (T14) + defer-max (T13)
__global__ __launch_bounds__(256) void attn_kernel(
    const unsigned short* __restrict__ qkv,
    unsigned short* __restrict__ ao)
{
    const int idx = blockIdx.x;
    const int qb = 15 - (idx >> 5);          // LPT: heavy blocks first
    const int bh = idx & 31;
    const int b = bh >> 4, h = bh & 15;
    const int tid = threadIdx.x, wave = tid >> 6, lane = tid & 63;
    const int c = lane & 15, g = lane >> 4;

    __shared__ unsigned short Ks[64 * 64];      // [kpos][d], XOR swz (row&7)<<4
    __shared__ unsigned short Vs[64 * 64];      // [d][kpos], XOR swz ((d&7)^(d>>3))<<4
    __shared__ unsigned short Ps[4][32 * 64];   // per-wave P [q][k], swz (row&7)<<4

    const size_t base = (size_t)b * SEQ * F3;
    const int qrow0 = qb * 128 + wave * 32;
    const float SC = 0.18033688011f;            // 0.125 * log2(e)

    // Q fragments (B-operand of swapped QK^T): [qt][dstep]
    bf16x8 qf[2][2];
#pragma unroll
    for (int qt = 0; qt < 2; qt++)
#pragma unroll
        for (int sdq = 0; sdq < 2; sdq++) {
            int row = qrow0 + qt * 16 + c;
            int d   = sdq * 32 + g * 8;
            qf[qt][sdq] = *reinterpret_cast<const bf16x8*>(qkv + base + (size_t)row * F3 + h * HD + d);
        }

    f32x4 po[2][4] = {};
    float mR[2], lR[2];
    mR[0] = mR[1] = -1e30f; lR[0] = lR[1] = 0.f;

    const int ktiles = (qb * 128 + 128) >> 6;
    const int ksrow = tid >> 3;          // 0..31 (K rows ksrow, 32+ksrow)
    const int sch   = tid & 7;           // 16B chunk within 128B row
    const int krow2 = (tid >> 3) * 2;    // V rows krow2, krow2+1

    const unsigned short* gK = qkv + base + EMB     + h * HD + sch * 8;
    const unsigned short* gV = qkv + base + 2 * EMB + h * HD + sch * 8;

    // prefetch tile 0 into registers
    bf16x8 kp0 = *reinterpret_cast<const bf16x8*>(gK + (size_t)ksrow * F3);
    bf16x8 kp1 = *reinterpret_cast<const bf16x8*>(gK + (size_t)(32 + ksrow) * F3);
    bf16x8 vp0 = *reinterpret_cast<const bf16x8*>(gV + (size_t)krow2 * F3);
    bf16x8 vp1 = *reinterpret_cast<const bf16x8*>(gV + (size_t)(krow2 + 1) * F3);

    for (int kt_i = 0; kt_i < ktiles; kt_i++) {
        const int kbase = kt_i * 64;
        __syncthreads();   // previous tile's LDS reads complete
        // write staged K
        {
            int off0 = (ksrow * 128 + sch * 16) ^ ((ksrow & 7) << 4);
            *reinterpret_cast<bf16x8*>((char*)Ks + off0) = kp0;
            int r1 = 32 + ksrow;
            int off1 = (r1 * 128 + sch * 16) ^ ((r1 & 7) << 4);
            *reinterpret_cast<bf16x8*>((char*)Ks + off1) = kp1;
        }
        // write staged V transposed. swz((d&7)^(d>>3)) is conflict-free for the
        // 8-lane write phases (banks = u ^ perm) AND the b128 read phases.
#pragma unroll
        for (int j = 0; j < 8; j++) {
            int d = sch * 8 + j;
            int off = (d * 128 + krow2 * 2) ^ ((((d & 7) ^ (d >> 3)) & 7) << 4);
            ushort2 pr; pr.x = (unsigned short)vp0[j]; pr.y = (unsigned short)vp1[j];
            *reinterpret_cast<ushort2*>((char*)Vs + off) = pr;
        }
        __syncthreads();

        // prefetch next tile (in flight during compute below)
        if (kt_i + 1 < ktiles) {
            const int nb = kbase + 64;
            kp0 = *reinterpret_cast<const bf16x8*>(gK + (size_t)(nb + ksrow) * F3);
            kp1 = *reinterpret_cast<const bf16x8*>(gK + (size_t)(nb + 32 + ksrow) * F3);
            vp0 = *reinterpret_cast<const bf16x8*>(gV + (size_t)(nb + krow2) * F3);
            vp1 = *reinterpret_cast<const bf16x8*>(gV + (size_t)(nb + krow2 + 1) * F3);
        }

        const bool active = kbase <= qrow0 + 31;
        if (active) {
            // S^T = K @ Q^T : lane holds q = qt*16+c, k = kbase + kt*16 + g*4 + r
            f32x4 st[4][2] = {};
#pragma unroll
            for (int dstep = 0; dstep < 2; dstep++) {
                bf16x8 kf[4];
#pragma unroll
                for (int kt = 0; kt < 4; kt++) {
                    int row = kt * 16 + c;
                    int off = (row * 128 + dstep * 64 + g * 16) ^ ((row & 7) << 4);
                    kf[kt] = *reinterpret_cast<const bf16x8*>((char*)Ks + off);
                }
#pragma unroll
                for (int kt = 0; kt < 4; kt++)
#pragma unroll
                    for (int qt = 0; qt < 2; qt++)
                        st[kt][qt] = __builtin_amdgcn_mfma_f32_16x16x32_bf16(kf[kt], qf[qt][dstep], st[kt][qt], 0, 0, 0);
            }

            const bool needmask = (kbase + 63) > qrow0;
#pragma unroll
            for (int qt = 0; qt < 2; qt++) {
                const int q = qrow0 + qt * 16 + c;
                float mx = -3.0e38f;
#pragma unroll
                for (int kt = 0; kt < 4; kt++)
#pragma unroll
                    for (int r = 0; r < 4; r++) {
                        float v = st[kt][qt][r];
                        if (needmask) {
                            int k = kbase + kt * 16 + g * 4 + r;
                            if (k > q) v = -3.0e38f;
                        }
                        st[kt][qt][r] = v;
                        mx = fmaxf(mx, v);
                    }
                mx = fmaxf(mx, __shfl_xor(mx, 16));
                mx = fmaxf(mx, __shfl_xor(mx, 32));

                // defer-max (T13, THR=8 raw-score units)
                const bool skip = __all(mx - mR[qt] <= 8.0f);
                float mn = skip ? mR[qt] : fmaxf(mR[qt], mx);
                const float nmn = -mn * SC;
                float rs = 0.f;
#pragma unroll
                for (int kt = 0; kt < 4; kt++)
#pragma unroll
                    for (int r = 0; r < 4; r++) {
                        float p = __builtin_amdgcn_exp2f(__builtin_fmaf(st[kt][qt][r], SC, nmn));
                        st[kt][qt][r] = p;
                        rs += p;
                    }
                rs += __shfl_xor(rs, 16);
                rs += __shfl_xor(rs, 32);
                if (skip) {
                    lR[qt] += rs;
                } else {
                    float alpha = __builtin_amdgcn_exp2f((mR[qt] - mn) * SC);
                    mR[qt] = mn;
                    lR[qt] = lR[qt] * alpha + rs;
#pragma unroll
                    for (int r = 0; r < 4; r++) {
                        float ar = __shfl(alpha, (g << 2) + r);
#pragma unroll
                        for (int ni = 0; ni < 4; ni++) po[qt][ni][r] *= ar;
                    }
                }
            }

            // P -> wave LDS (packed cvt_pk + b64 writes)
            unsigned short* Pw = Ps[wave];
#pragma unroll
            for (int qt = 0; qt < 2; qt++) {
                int row = qt * 16 + c;
#pragma unroll
                for (int kt = 0; kt < 4; kt++) {
                    uint2 pk;
                    pk.x = pk_bf16(st[kt][qt][0], st[kt][qt][1]);
                    pk.y = pk_bf16(st[kt][qt][2], st[kt][qt][3]);
                    int off = (row * 128 + kt * 32 + g * 8) ^ ((row & 7) << 4);
                    *reinterpret_cast<uint2*>((char*)Pw + off) = pk;
                }
            }

            // PV: O[q][d] += P @ V
#pragma unroll
            for (int s2 = 0; s2 < 2; s2++) {
                bf16x8 pa[2], vb[4];
#pragma unroll
                for (int mi = 0; mi < 2; mi++) {
                    int row = mi * 16 + c;
                    int off = (row * 128 + s2 * 64 + g * 16) ^ ((row & 7) << 4);
                    pa[mi] = *reinterpret_cast<const bf16x8*>((char*)Pw + off);
                }
#pragma unroll
                for (int ni = 0; ni < 4; ni++) {
                    int n = ni * 16 + c;
                    int off = (n * 128 + s2 * 64 + g * 16) ^ ((((n & 7) ^ (n >> 3)) & 7) << 4);
                    vb[ni] = *reinterpret_cast<const bf16x8*>((char*)Vs + off);
                }
#pragma unroll
                for (int mi = 0; mi < 2; mi++)
#pragma unroll
                    for (int ni = 0; ni < 4; ni++)
                        po[mi][ni] = __builtin_amdgcn_mfma_f32_16x16x32_bf16(pa[mi], vb[ni], po[mi][ni], 0, 0, 0);
            }
        }
    }

    // epilogue
#pragma unroll
    for (int qt = 0; qt < 2; qt++) {
        float invl = 1.0f / lR[qt];
#pragma unroll
        for (int r = 0; r < 4; r++) {
            float iv = __shfl(invl, (g << 2) + r);
            int row = qrow0 + qt * 16 + g * 4 + r;
#pragma unroll
            for (int ni = 0; ni < 4; ni++) {
                int d = ni * 16 + c;
                ao[(size_t)(b * SEQ + row) * EMB + h * HD + d] = f2bf(po[qt][ni][r] * iv);
            }
        }
    }
}

// ---------------- launch ----------------
extern "C" void kernel_launch(void* const* d_in, const int* in_sizes, int n_in,
                              void* d_out, int out_size, void* d_ws, size_t ws_size,
                              hipStream_t stream)
{
    const float* x    = (const float*)d_in[0];
    const float* Win  = (const float*)d_in[1];
    const float* Wout = (const float*)d_in[2];
    float* out = (float*)d_out;

    char* ws = (char*)d_ws;
    unsigned short* xb    = (unsigned short*)(ws);
    unsigned short* winb  = (unsigned short*)(ws + (8u  << 20));
    unsigned short* woutb = (unsigned short*)(ws + (14u << 20));
    unsigned short* qkvb  = (unsigned short*)(ws + (16u << 20));
    unsigned short* aob   = (unsigned short*)(ws + (40u << 20));

    const int nx    = BS * SEQ * EMB;
    const int nwin  = F3 * EMB;
    const int nwout = EMB * EMB;

    cvt_kernel<<<nx    / 4 / 256, 256, 0, stream>>>(x,    xb,    nx / 4);
    cvt_kernel<<<nwin  / 4 / 256, 256, 0, stream>>>(Win,  winb,  nwin / 4);
    cvt_kernel<<<nwout / 4 / 256, 256, 0, stream>>>(Wout, woutb, nwout / 4);

    // GEMM1: [4096,1024] @ [3072,1024]^T -> grid 24x32 = 768 (768%8==0)
    gemm_bt<true><<<dim3(768), 256, 0, stream>>>(xb, winb, (void*)qkvb, BS * SEQ, F3, EMB, F3 / 128);

    attn_kernel<<<dim3(512), 256, 0, stream>>>(qkvb, aob);

    // GEMM2: [4096,1024] @ [1024,1024]^T -> grid 8x32 = 256 (256%8==0)
    gemm_bt<false><<<dim3(256), 256, 0, stream>>>(aob, woutb, (void*)out, BS * SEQ, EMB, EMB, EMB / 128);
}

// Round 8
// 191.565 us; speedup vs baseline: 1.7095x; 1.0747x over previous
//
#include <hip/hip_runtime.h>
#include <stdint.h>

#define SEQ 2048
#define BS 2
#define EMB 1024
#define NH 16
#define HD 64
#define F3 3072

using f32x4 = __attribute__((ext_vector_type(4))) float;
using bf16x8 = __attribute__((ext_vector_type(8))) short;

__device__ __forceinline__ unsigned short f2bf(float f) {
    union { float f; uint32_t u; } v; v.f = f;
    uint32_t u = v.u;
    u = u + 0x7FFFu + ((u >> 16) & 1u);   // RNE
    return (unsigned short)(u >> 16);
}

// v_cvt_pk_bf16_f32: dst = {hi16=cvt(b), lo16=cvt(a)}  (no builtin on gfx950 — T12 recipe)
__device__ __forceinline__ uint32_t pk_bf16(float a, float b) {
    uint32_t r;
    asm("v_cvt_pk_bf16_f32 %0, %1, %2" : "=v"(r) : "v"(a), "v"(b));
    return r;
}

#define GLOAD_LDS16(g, l) \
    __builtin_amdgcn_global_load_lds((const __attribute__((address_space(1))) void*)(g), \
                                     (__attribute__((address_space(3))) void*)(l), 16, 0, 0)

// ---------------- fp32 -> bf16 conversion ----------------
__global__ void cvt_kernel(const float* __restrict__ in, unsigned short* __restrict__ out, int n4) {
    int i = blockIdx.x * blockDim.x + threadIdx.x;
    if (i < n4) {
        f32x4 v = reinterpret_cast<const f32x4*>(in)[i];
        uint2 o;
        o.x = pk_bf16(v.x, v.y);
        o.y = pk_bf16(v.z, v.w);
        reinterpret_cast<uint2*>(out)[i] = o;
    }
}

// ---------------- GEMM: C[M,N] = A[M,K] @ B[N,K]^T, 1D grid + XCD swizzle ----------------
template <bool BF16OUT>
__global__ __launch_bounds__(256) void gemm_bt(
    const unsigned short* __restrict__ A,
    const unsigned short* __restrict__ B,
    void* __restrict__ Cv,
    int M, int N, int K, int nbx)
{
    __shared__ unsigned short As[128 * 32];
    __shared__ unsigned short Bs[128 * 32];
    const int tid  = threadIdx.x;
    const int wave = tid >> 6, lane = tid & 63;
    const int wr = wave >> 1, wc = wave & 1;

    const int nwg = gridDim.x;
    const int s = (blockIdx.x & 7) * (nwg >> 3) + (blockIdx.x >> 3);
    const int bx = s % nbx, by = s / nbx;
    const int row0 = by * 128, col0 = bx * 128;

    f32x4 acc[4][4] = {};

    const int srow = wave * 16 + (lane >> 2);
    const int scol = (lane & 3) * 8;

    const unsigned short* gA = A + (size_t)(row0 + srow) * K + scol;
    const unsigned short* gB = B + (size_t)(col0 + srow) * K + scol;
    unsigned short* lA = As + wave * 16 * 32;
    unsigned short* lB = Bs + wave * 16 * 32;

    for (int kb = 0; kb < K; kb += 32) {
        __syncthreads();
        GLOAD_LDS16(gA + kb,                    lA);
        GLOAD_LDS16(gA + (size_t)64 * K + kb,   lA + 64 * 32);
        GLOAD_LDS16(gB + kb,                    lB);
        GLOAD_LDS16(gB + (size_t)64 * K + kb,   lB + 64 * 32);
        asm volatile("s_waitcnt vmcnt(0)" ::: "memory");
        __syncthreads();

        bf16x8 af[4], bfr[4];
#pragma unroll
        for (int mi = 0; mi < 4; mi++)
            af[mi] = *reinterpret_cast<const bf16x8*>(As + (wr * 64 + mi * 16 + (lane & 15)) * 32 + (lane >> 4) * 8);
#pragma unroll
        for (int ni = 0; ni < 4; ni++)
            bfr[ni] = *reinterpret_cast<const bf16x8*>(Bs + (wc * 64 + ni * 16 + (lane & 15)) * 32 + (lane >> 4) * 8);
#pragma unroll
        for (int mi = 0; mi < 4; mi++)
#pragma unroll
            for (int ni = 0; ni < 4; ni++)
                acc[mi][ni] = __builtin_amdgcn_mfma_f32_16x16x32_bf16(af[mi], bfr[ni], acc[mi][ni], 0, 0, 0);
    }

#pragma unroll
    for (int mi = 0; mi < 4; mi++)
#pragma unroll
        for (int ni = 0; ni < 4; ni++)
#pragma unroll
            for (int r = 0; r < 4; r++) {
                int row = row0 + wr * 64 + mi * 16 + (lane >> 4) * 4 + r;
                int col = col0 + wc * 64 + ni * 16 + (lane & 15);
                float v = acc[mi][ni][r];
                if constexpr (BF16OUT)
                    ((unsigned short*)Cv)[(size_t)row * N + col] = f2bf(v);
                else
                    ((float*)Cv)[(size_t)row * N + col] = v;
            }
}

// ---------------- causal flash attention ----------------
// QBLK=64: 4 waves x 16 q-rows. swapped-QK^T in-reg softmax, reg-prefetch (T14),
// defer-max (T13), bh->XCD affinity (KV L2-resident) + LPT.
__global__ __launch_bounds__(256) void attn_kernel(
    const unsigned short* __restrict__ qkv,
    unsigned short* __restrict__ ao)
{
    const int o = blockIdx.x;                 // 0..1023
    const int pos = o >> 3;
    const int bh = (o & 7) * 4 + (pos & 3);   // 4 heads per XCD -> KV fits 4MB L2
    const int qb = 31 - (pos >> 2);           // LPT: heavy q-blocks first
    const int b = bh >> 4, h = bh & 15;
    const int tid = threadIdx.x, wave = tid >> 6, lane = tid & 63;
    const int c = lane & 15, g = lane >> 4;

    __shared__ unsigned short Ks[64 * 64];      // [kpos][d], swz (row&7)<<4
    __shared__ unsigned short Vs[64 * 64];      // [d][kpos], swz ((d&7)^(d>>3))<<4
    __shared__ unsigned short Ps[4][16 * 64];   // per-wave P [q][k], swz (row&7)<<4

    const size_t base = (size_t)b * SEQ * F3;
    const int qrow0 = qb * 64 + wave * 16;
    const float SC = 0.18033688011f;            // 0.125 * log2(e)

    // Q fragments (B-operand of swapped QK^T): [dstep]
    bf16x8 qf[2];
#pragma unroll
    for (int sdq = 0; sdq < 2; sdq++) {
        int row = qrow0 + c;
        int d   = sdq * 32 + g * 8;
        qf[sdq] = *reinterpret_cast<const bf16x8*>(qkv + base + (size_t)row * F3 + h * HD + d);
    }

    f32x4 po[4] = {};
    float mR = -1e30f, lR = 0.f;

    const int ktiles = qb + 1;           // all waves active on every tile
    const int ksrow = tid >> 3;          // 0..31 (K rows ksrow, 32+ksrow)
    const int sch   = tid & 7;           // 16B chunk within 128B row
    const int krow2 = (tid >> 3) * 2;    // V rows krow2, krow2+1

    const unsigned short* gK = qkv + base + EMB     + h * HD + sch * 8;
    const unsigned short* gV = qkv + base + 2 * EMB + h * HD + sch * 8;

    // prefetch tile 0 into registers (T14)
    bf16x8 kp0 = *reinterpret_cast<const bf16x8*>(gK + (size_t)ksrow * F3);
    bf16x8 kp1 = *reinterpret_cast<const bf16x8*>(gK + (size_t)(32 + ksrow) * F3);
    bf16x8 vp0 = *reinterpret_cast<const bf16x8*>(gV + (size_t)krow2 * F3);
    bf16x8 vp1 = *reinterpret_cast<const bf16x8*>(gV + (size_t)(krow2 + 1) * F3);

    for (int kt_i = 0; kt_i < ktiles; kt_i++) {
        const int kbase = kt_i * 64;
        __syncthreads();   // previous tile's LDS reads complete
        // write staged K
        {
            int off0 = (ksrow * 128 + sch * 16) ^ ((ksrow & 7) << 4);
            *reinterpret_cast<bf16x8*>((char*)Ks + off0) = kp0;
            int r1 = 32 + ksrow;
            int off1 = (r1 * 128 + sch * 16) ^ ((r1 & 7) << 4);
            *reinterpret_cast<bf16x8*>((char*)Ks + off1) = kp1;
        }
        // write staged V transposed
#pragma unroll
        for (int j = 0; j < 8; j++) {
            int d = sch * 8 + j;
            int off = (d * 128 + krow2 * 2) ^ ((((d & 7) ^ (d >> 3)) & 7) << 4);
            ushort2 pr; pr.x = (unsigned short)vp0[j]; pr.y = (unsigned short)vp1[j];
            *reinterpret_cast<ushort2*>((char*)Vs + off) = pr;
        }
        __syncthreads();

        // prefetch next tile (in flight during compute below)
        if (kt_i + 1 < ktiles) {
            const int nb = kbase + 64;
            kp0 = *reinterpret_cast<const bf16x8*>(gK + (size_t)(nb + ksrow) * F3);
            kp1 = *reinterpret_cast<const bf16x8*>(gK + (size_t)(nb + 32 + ksrow) * F3);
            vp0 = *reinterpret_cast<const bf16x8*>(gV + (size_t)(nb + krow2) * F3);
            vp1 = *reinterpret_cast<const bf16x8*>(gV + (size_t)(nb + krow2 + 1) * F3);
        }

        // S^T = K @ Q^T : lane holds q = qrow0 + c, k = kbase + kt*16 + g*4 + r
        f32x4 st[4] = {};
#pragma unroll
        for (int dstep = 0; dstep < 2; dstep++) {
            bf16x8 kf[4];
#pragma unroll
            for (int kt = 0; kt < 4; kt++) {
                int row = kt * 16 + c;
                int off = (row * 128 + dstep * 64 + g * 16) ^ ((row & 7) << 4);
                kf[kt] = *reinterpret_cast<const bf16x8*>((char*)Ks + off);
            }
#pragma unroll
            for (int kt = 0; kt < 4; kt++)
                st[kt] = __builtin_amdgcn_mfma_f32_16x16x32_bf16(kf[kt], qf[dstep], st[kt], 0, 0, 0);
        }

        const bool needmask = (kt_i == qb);   // only the diagonal tile needs masking
        {
            const int q = qrow0 + c;
            float mx = -3.0e38f;
#pragma unroll
            for (int kt = 0; kt < 4; kt++)
#pragma unroll
                for (int r = 0; r < 4; r++) {
                    float v = st[kt][r];
                    if (needmask) {
                        int k = kbase + kt * 16 + g * 4 + r;
                        if (k > q) v = -3.0e38f;
                    }
                    st[kt][r] = v;
                    mx = fmaxf(mx, v);
                }
            mx = fmaxf(mx, __shfl_xor(mx, 16));
            mx = fmaxf(mx, __shfl_xor(mx, 32));

            // defer-max (T13, THR=8 raw-score units)
            const bool skip = __all(mx - mR <= 8.0f);
            float mn = skip ? mR : fmaxf(mR, mx);
            const float nmn = -mn * SC;
            float rs = 0.f;
#pragma unroll
            for (int kt = 0; kt < 4; kt++)
#pragma unroll
                for (int r = 0; r < 4; r++) {
                    float p = __builtin_amdgcn_exp2f(__builtin_fmaf(st[kt][r], SC, nmn));
                    st[kt][r] = p;
                    rs += p;
                }
            rs += __shfl_xor(rs, 16);
            rs += __shfl_xor(rs, 32);
            if (skip) {
                lR += rs;
            } else {
                float alpha = __builtin_amdgcn_exp2f((mR - mn) * SC);
                mR = mn;
                lR = lR * alpha + rs;
#pragma unroll
                for (int r = 0; r < 4; r++) {
                    float ar = __shfl(alpha, (g << 2) + r);
#pragma unroll
                    for (int ni = 0; ni < 4; ni++) po[ni][r] *= ar;
                }
            }
        }

        // P -> wave LDS (packed cvt_pk + b64 writes)
        unsigned short* Pw = Ps[wave];
        {
            int row = c;
#pragma unroll
            for (int kt = 0; kt < 4; kt++) {
                uint2 pk;
                pk.x = pk_bf16(st[kt][0], st[kt][1]);
                pk.y = pk_bf16(st[kt][2], st[kt][3]);
                int off = (row * 128 + kt * 32 + g * 8) ^ ((row & 7) << 4);
                *reinterpret_cast<uint2*>((char*)Pw + off) = pk;
            }
        }

        // PV: O[q][d] += P @ V
#pragma unroll
        for (int s2 = 0; s2 < 2; s2++) {
            bf16x8 pa, vb[4];
            {
                int row = c;
                int off = (row * 128 + s2 * 64 + g * 16) ^ ((row & 7) << 4);
                pa = *reinterpret_cast<const bf16x8*>((char*)Pw + off);
            }
#pragma unroll
            for (int ni = 0; ni < 4; ni++) {
                int n = ni * 16 + c;
                int off = (n * 128 + s2 * 64 + g * 16) ^ ((((n & 7) ^ (n >> 3)) & 7) << 4);
                vb[ni] = *reinterpret_cast<const bf16x8*>((char*)Vs + off);
            }
#pragma unroll
            for (int ni = 0; ni < 4; ni++)
                po[ni] = __builtin_amdgcn_mfma_f32_16x16x32_bf16(pa, vb[ni], po[ni], 0, 0, 0);
        }
    }

    // epilogue
    {
        float invl = 1.0f / lR;
#pragma unroll
        for (int r = 0; r < 4; r++) {
            float iv = __shfl(invl, (g << 2) + r);
            int row = qrow0 + g * 4 + r;
#pragma unroll
            for (int ni = 0; ni < 4; ni++) {
                int d = ni * 16 + c;
                ao[(size_t)(b * SEQ + row) * EMB + h * HD + d] = f2bf(po[ni][r] * iv);
            }
        }
    }
}

// ---------------- launch ----------------
extern "C" void kernel_launch(void* const* d_in, const int* in_sizes, int n_in,
                              void* d_out, int out_size, void* d_ws, size_t ws_size,
                              hipStream_t stream)
{
    const float* x    = (const float*)d_in[0];
    const float* Win  = (const float*)d_in[1];
    const float* Wout = (const float*)d_in[2];
    float* out = (float*)d_out;

    char* ws = (char*)d_ws;
    unsigned short* xb    = (unsigned short*)(ws);
    unsigned short* winb  = (unsigned short*)(ws + (8u  << 20));
    unsigned short* woutb = (unsigned short*)(ws + (14u << 20));
    unsigned short* qkvb  = (unsigned short*)(ws + (16u << 20));
    unsigned short* aob   = (unsigned short*)(ws + (40u << 20));

    const int nx    = BS * SEQ * EMB;
    const int nwin  = F3 * EMB;
    const int nwout = EMB * EMB;

    cvt_kernel<<<nx    / 4 / 256, 256, 0, stream>>>(x,    xb,    nx / 4);
    cvt_kernel<<<nwin  / 4 / 256, 256, 0, stream>>>(Win,  winb,  nwin / 4);
    cvt_kernel<<<nwout / 4 / 256, 256, 0, stream>>>(Wout, woutb, nwout / 4);

    // GEMM1: [4096,1024] @ [3072,1024]^T -> grid 24x32 = 768 (768%8==0)
    gemm_bt<true><<<dim3(768), 256, 0, stream>>>(xb, winb, (void*)qkvb, BS * SEQ, F3, EMB, F3 / 128);

    // attn: 32 qb x 32 bh = 1024 blocks
    attn_kernel<<<dim3(1024), 256, 0, stream>>>(qkvb, aob);

    // GEMM2: [4096,1024] @ [1024,1024]^T -> grid 8x32 = 256 (256%8==0)
    gemm_bt<false><<<dim3(256), 256, 0, stream>>>(aob, woutb, (void*)out, BS * SEQ, EMB, EMB, EMB / 128);
}

// Round 10
// 180.578 us; speedup vs baseline: 1.8135x; 1.0608x over previous
//
#include <hip/hip_runtime.h>
#include <stdint.h>

#define SEQ 2048
#define BS 2
#define EMB 1024
#define NH 16
#define HD 64
#define F3 3072

using f32x4 = __attribute__((ext_vector_type(4))) float;
using bf16x8 = __attribute__((ext_vector_type(8))) short;

__device__ __forceinline__ unsigned short f2bf(float f) {
    union { float f; uint32_t u; } v; v.f = f;
    uint32_t u = v.u;
    u = u + 0x7FFFu + ((u >> 16) & 1u);   // RNE
    return (unsigned short)(u >> 16);
}

// v_cvt_pk_bf16_f32: dst = {hi16=cvt(b), lo16=cvt(a)}
__device__ __forceinline__ uint32_t pk_bf16(float a, float b) {
    uint32_t r;
    asm("v_cvt_pk_bf16_f32 %0, %1, %2" : "=v"(r) : "v"(a), "v"(b));
    return r;
}

#define GLOAD_LDS16(g, l) \
    __builtin_amdgcn_global_load_lds((const __attribute__((address_space(1))) void*)(g), \
                                     (__attribute__((address_space(3))) void*)(l), 16, 0, 0)

// ---------------- fp32 -> bf16 conversion ----------------
__global__ void cvt_kernel(const float* __restrict__ in, unsigned short* __restrict__ out, int n4) {
    int i = blockIdx.x * blockDim.x + threadIdx.x;
    if (i < n4) {
        f32x4 v = reinterpret_cast<const f32x4*>(in)[i];
        uint2 o;
        o.x = pk_bf16(v.x, v.y);
        o.y = pk_bf16(v.z, v.w);
        reinterpret_cast<uint2*>(out)[i] = o;
    }
}

// ---------------- GEMM: C[M,N] = A[M,K] @ B[N,K]^T ----------------
// 2-phase double-buffered LDS (T3-minimum). QKV mode: V-third columns are
// written TRANSPOSED into vT[b][h][d][s] instead of row-major into C.
template <bool QKV>
__global__ __launch_bounds__(256) void gemm_bt(
    const unsigned short* __restrict__ A,
    const unsigned short* __restrict__ B,
    void* __restrict__ Cv,
    unsigned short* __restrict__ vT,
    int M, int N, int K, int nbx)
{
    __shared__ unsigned short As[2][128 * 32];
    __shared__ unsigned short Bs[2][128 * 32];
    const int tid  = threadIdx.x;
    const int wave = tid >> 6, lane = tid & 63;
    const int wr = wave >> 1, wc = wave & 1;

    const int nwg = gridDim.x;
    const int sw = (blockIdx.x & 7) * (nwg >> 3) + (blockIdx.x >> 3);
    const int bx = sw % nbx, by = sw / nbx;
    const int row0 = by * 128, col0 = bx * 128;

    f32x4 acc[4][4] = {};

    const int srow = wave * 16 + (lane >> 2);
    const int scol = (lane & 3) * 8;

    const unsigned short* gA = A + (size_t)(row0 + srow) * K + scol;
    const unsigned short* gB = B + (size_t)(col0 + srow) * K + scol;
    const int lofs = wave * 16 * 32;

#define STAGE_G(buf, kb) do { \
    GLOAD_LDS16(gA + (kb),                   As[buf] + lofs); \
    GLOAD_LDS16(gA + (size_t)64 * K + (kb),  As[buf] + 64 * 32 + lofs); \
    GLOAD_LDS16(gB + (kb),                   Bs[buf] + lofs); \
    GLOAD_LDS16(gB + (size_t)64 * K + (kb),  Bs[buf] + 64 * 32 + lofs); } while (0)

    STAGE_G(0, 0);
    asm volatile("s_waitcnt vmcnt(0)" ::: "memory");
    __syncthreads();

    int cur = 0;
    for (int kb = 0; kb < K; kb += 32) {
        if (kb + 32 < K) STAGE_G(cur ^ 1, kb + 32);   // issue BEFORE compute (T3)

        bf16x8 af[4], bfr[4];
#pragma unroll
        for (int mi = 0; mi < 4; mi++)
            af[mi] = *reinterpret_cast<const bf16x8*>(As[cur] + (wr * 64 + mi * 16 + (lane & 15)) * 32 + (lane >> 4) * 8);
#pragma unroll
        for (int ni = 0; ni < 4; ni++)
            bfr[ni] = *reinterpret_cast<const bf16x8*>(Bs[cur] + (wc * 64 + ni * 16 + (lane & 15)) * 32 + (lane >> 4) * 8);
#pragma unroll
        for (int mi = 0; mi < 4; mi++)
#pragma unroll
            for (int ni = 0; ni < 4; ni++)
                acc[mi][ni] = __builtin_amdgcn_mfma_f32_16x16x32_bf16(af[mi], bfr[ni], acc[mi][ni], 0, 0, 0);

        asm volatile("s_waitcnt vmcnt(0)" ::: "memory");
        __syncthreads();
        cur ^= 1;
    }
#undef STAGE_G

    if constexpr (QKV) {
        if (col0 >= 2 * EMB) {
            // V columns -> vT[b][h][d][s], packed 4-row 8B stores
#pragma unroll
            for (int mi = 0; mi < 4; mi++)
#pragma unroll
                for (int ni = 0; ni < 4; ni++) {
                    int vcol = col0 - 2 * EMB + wc * 64 + ni * 16 + (lane & 15);
                    int hh = vcol >> 6, dd = vcol & 63;
                    int row = row0 + wr * 64 + mi * 16 + (lane >> 4) * 4;
                    int bb = row >> 11, ss = row & 2047;
                    uint2 pk;
                    pk.x = pk_bf16(acc[mi][ni][0], acc[mi][ni][1]);
                    pk.y = pk_bf16(acc[mi][ni][2], acc[mi][ni][3]);
                    *reinterpret_cast<uint2*>(vT + (size_t)((bb * 16 + hh) * 64 + dd) * 2048 + ss) = pk;
                }
        } else {
#pragma unroll
            for (int mi = 0; mi < 4; mi++)
#pragma unroll
                for (int ni = 0; ni < 4; ni++)
#pragma unroll
                    for (int r = 0; r < 4; r++) {
                        int row = row0 + wr * 64 + mi * 16 + (lane >> 4) * 4 + r;
                        int col = col0 + wc * 64 + ni * 16 + (lane & 15);
                        ((unsigned short*)Cv)[(size_t)row * N + col] = f2bf(acc[mi][ni][r]);
                    }
        }
    } else {
#pragma unroll
        for (int mi = 0; mi < 4; mi++)
#pragma unroll
            for (int ni = 0; ni < 4; ni++)
#pragma unroll
                for (int r = 0; r < 4; r++) {
                    int row = row0 + wr * 64 + mi * 16 + (lane >> 4) * 4 + r;
                    int col = col0 + wc * 64 + ni * 16 + (lane & 15);
                    ((float*)Cv)[(size_t)row * N + col] = acc[mi][ni][r];
                }
    }
}

// ---------------- causal flash attention ----------------
// QBLK=64, 4 waves x 16 q-rows. swapped-QK^T in-reg softmax, reg-prefetch (T14),
// defer-max (T13), pre-transposed V (from GEMM1), bh->XCD affinity + LPT.
__global__ __launch_bounds__(256) void attn_kernel(
    const unsigned short* __restrict__ qkv,
    const unsigned short* __restrict__ vT,
    unsigned short* __restrict__ ao)
{
    const int o = blockIdx.x;                 // 0..1023
    const int pos = o >> 3;
    const int bh = (o & 7) * 4 + (pos & 3);   // 4 heads per XCD -> KV fits L2
    const int qb = 31 - (pos >> 2);           // LPT: heavy q-blocks first
    const int b = bh >> 4, h = bh & 15;
    const int tid = threadIdx.x, wave = tid >> 6, lane = tid & 63;
    const int c = lane & 15, g = lane >> 4;

    __shared__ unsigned short Ks[64 * 64];      // [kpos][d], swz (row&7)<<4
    __shared__ unsigned short Vs[64 * 64];      // [d][kpos], swz ((d&7)^(d>>3))<<4
    __shared__ unsigned short Ps[4][16 * 64];   // per-wave P [q][k], swz (row&7)<<4

    const size_t base = (size_t)b * SEQ * F3;
    const int qrow0 = qb * 64 + wave * 16;
    const float SC = 0.18033688011f;            // 0.125 * log2(e)

    // Q fragments (B-operand of swapped QK^T)
    bf16x8 qf[2];
#pragma unroll
    for (int sdq = 0; sdq < 2; sdq++) {
        int row = qrow0 + c;
        int d   = sdq * 32 + g * 8;
        qf[sdq] = *reinterpret_cast<const bf16x8*>(qkv + base + (size_t)row * F3 + h * HD + d);
    }

    f32x4 po[4] = {};
    float mR = -1e30f, lR = 0.f;

    const int ktiles = qb + 1;
    const int vrow = tid >> 3;           // 0..31 (rows vrow, vrow+32)
    const int sch  = tid & 7;            // 16B chunk within 128B row

    const unsigned short* gK  = qkv + base + EMB + h * HD + sch * 8;
    const unsigned short* gVT = vT + (size_t)bh * 64 * SEQ + sch * 8;

    // prefetch tile 0 (T14)
    bf16x8 kp0 = *reinterpret_cast<const bf16x8*>(gK + (size_t)vrow * F3);
    bf16x8 kp1 = *reinterpret_cast<const bf16x8*>(gK + (size_t)(32 + vrow) * F3);
    bf16x8 vp0 = *reinterpret_cast<const bf16x8*>(gVT + (size_t)vrow * SEQ);
    bf16x8 vp1 = *reinterpret_cast<const bf16x8*>(gVT + (size_t)(32 + vrow) * SEQ);

    for (int kt_i = 0; kt_i < ktiles; kt_i++) {
        const int kbase = kt_i * 64;
        __syncthreads();   // previous tile's LDS reads complete
        {
            int off0 = (vrow * 128 + sch * 16) ^ ((vrow & 7) << 4);
            *reinterpret_cast<bf16x8*>((char*)Ks + off0) = kp0;
            int r1 = 32 + vrow;
            int off1 = (r1 * 128 + sch * 16) ^ ((r1 & 7) << 4);
            *reinterpret_cast<bf16x8*>((char*)Ks + off1) = kp1;
            int vo0 = (vrow * 128 + sch * 16) ^ ((((vrow & 7) ^ (vrow >> 3)) & 7) << 4);
            *reinterpret_cast<bf16x8*>((char*)Vs + vo0) = vp0;
            int vo1 = (r1 * 128 + sch * 16) ^ ((((r1 & 7) ^ (r1 >> 3)) & 7) << 4);
            *reinterpret_cast<bf16x8*>((char*)Vs + vo1) = vp1;
        }
        __syncthreads();

        // prefetch next tile
        if (kt_i + 1 < ktiles) {
            const int nb = kbase + 64;
            kp0 = *reinterpret_cast<const bf16x8*>(gK + (size_t)(nb + vrow) * F3);
            kp1 = *reinterpret_cast<const bf16x8*>(gK + (size_t)(nb + 32 + vrow) * F3);
            vp0 = *reinterpret_cast<const bf16x8*>(gVT + (size_t)vrow * SEQ + nb);
            vp1 = *reinterpret_cast<const bf16x8*>(gVT + (size_t)(32 + vrow) * SEQ + nb);
        }

        // S^T = K @ Q^T : lane holds q = qrow0 + c, k = kbase + kt*16 + g*4 + r
        f32x4 st[4] = {};
#pragma unroll
        for (int dstep = 0; dstep < 2; dstep++) {
            bf16x8 kf[4];
#pragma unroll
            for (int kt = 0; kt < 4; kt++) {
                int row = kt * 16 + c;
                int off = (row * 128 + dstep * 64 + g * 16) ^ ((row & 7) << 4);
                kf[kt] = *reinterpret_cast<const bf16x8*>((char*)Ks + off);
            }
#pragma unroll
            for (int kt = 0; kt < 4; kt++)
                st[kt] = __builtin_amdgcn_mfma_f32_16x16x32_bf16(kf[kt], qf[dstep], st[kt], 0, 0, 0);
        }

        const bool needmask = (kt_i == qb);
        {
            const int q = qrow0 + c;
            float mx = -3.0e38f;
#pragma unroll
            for (int kt = 0; kt < 4; kt++)
#pragma unroll
                for (int r = 0; r < 4; r++) {
                    float v = st[kt][r];
                    if (needmask) {
                        int k = kbase + kt * 16 + g * 4 + r;
                        if (k > q) v = -3.0e38f;
                    }
                    st[kt][r] = v;
                    mx = fmaxf(mx, v);
                }
            mx = fmaxf(mx, __shfl_xor(mx, 16));
            mx = fmaxf(mx, __shfl_xor(mx, 32));

            const bool skip = __all(mx - mR <= 8.0f);   // T13
            float mn = skip ? mR : fmaxf(mR, mx);
            const float nmn = -mn * SC;
            float rs = 0.f;
#pragma unroll
            for (int kt = 0; kt < 4; kt++)
#pragma unroll
                for (int r = 0; r < 4; r++) {
                    float p = __builtin_amdgcn_exp2f(__builtin_fmaf(st[kt][r], SC, nmn));
                    st[kt][r] = p;
                    rs += p;
                }
            rs += __shfl_xor(rs, 16);
            rs += __shfl_xor(rs, 32);
            if (skip) {
                lR += rs;
            } else {
                float alpha = __builtin_amdgcn_exp2f((mR - mn) * SC);
                mR = mn;
                lR = lR * alpha + rs;
#pragma unroll
                for (int r = 0; r < 4; r++) {
                    float ar = __shfl(alpha, (g << 2) + r);
#pragma unroll
                    for (int ni = 0; ni < 4; ni++) po[ni][r] *= ar;
                }
            }
        }

        // P -> wave LDS (cvt_pk + b64 writes)
        unsigned short* Pw = Ps[wave];
        {
#pragma unroll
            for (int kt = 0; kt < 4; kt++) {
                uint2 pk;
                pk.x = pk_bf16(st[kt][0], st[kt][1]);
                pk.y = pk_bf16(st[kt][2], st[kt][3]);
                int off = (c * 128 + kt * 32 + g * 8) ^ ((c & 7) << 4);
                *reinterpret_cast<uint2*>((char*)Pw + off) = pk;
            }
        }

        // PV: O[q][d] += P @ V
#pragma unroll
        for (int s2 = 0; s2 < 2; s2++) {
            bf16x8 pa, vb[4];
            {
                int off = (c * 128 + s2 * 64 + g * 16) ^ ((c & 7) << 4);
                pa = *reinterpret_cast<const bf16x8*>((char*)Pw + off);
            }
#pragma unroll
            for (int ni = 0; ni < 4; ni++) {
                int n = ni * 16 + c;
                int off = (n * 128 + s2 * 64 + g * 16) ^ ((((n & 7) ^ (n >> 3)) & 7) << 4);
                vb[ni] = *reinterpret_cast<const bf16x8*>((char*)Vs + off);
            }
#pragma unroll
            for (int ni = 0; ni < 4; ni++)
                po[ni] = __builtin_amdgcn_mfma_f32_16x16x32_bf16(pa, vb[ni], po[ni], 0, 0, 0);
        }
    }

    // epilogue
    {
        float invl = 1.0f / lR;
#pragma unroll
        for (int r = 0; r < 4; r++) {
            float iv = __shfl(invl, (g << 2) + r);
            int row = qrow0 + g * 4 + r;
#pragma unroll
            for (int ni = 0; ni < 4; ni++) {
                int d = ni * 16 + c;
                ao[(size_t)(b * SEQ + row) * EMB + h * HD + d] = f2bf(po[ni][r] * iv);
            }
        }
    }
}

// ---------------- launch ----------------
extern "C" void kernel_launch(void* const* d_in, const int* in_sizes, int n_in,
                              void* d_out, int out_size, void* d_ws, size_t ws_size,
                              hipStream_t stream)
{
    const float* x    = (const float*)d_in[0];
    const float* Win  = (const float*)d_in[1];
    const float* Wout = (const float*)d_in[2];
    float* out = (float*)d_out;

    char* ws = (char*)d_ws;
    unsigned short* xb    = (unsigned short*)(ws);                  //  8 MB
    unsigned short* winb  = (unsigned short*)(ws + (8u  << 20));    //  6 MB
    unsigned short* woutb = (unsigned short*)(ws + (14u << 20));    //  2 MB
    unsigned short* qkvb  = (unsigned short*)(ws + (16u << 20));    // 24 MB (V third unused)
    unsigned short* aob   = (unsigned short*)(ws + (40u << 20));    //  8 MB
    unsigned short* vtb   = (unsigned short*)(ws + (48u << 20));    //  8 MB  V^T [b][h][d][s]

    const int nx    = BS * SEQ * EMB;
    const int nwin  = F3 * EMB;
    const int nwout = EMB * EMB;

    cvt_kernel<<<nx    / 4 / 256, 256, 0, stream>>>(x,    xb,    nx / 4);
    cvt_kernel<<<nwin  / 4 / 256, 256, 0, stream>>>(Win,  winb,  nwin / 4);
    cvt_kernel<<<nwout / 4 / 256, 256, 0, stream>>>(Wout, woutb, nwout / 4);

    // GEMM1: [4096,1024] @ [3072,1024]^T ; V third -> vtb transposed
    gemm_bt<true><<<dim3(768), 256, 0, stream>>>(xb, winb, (void*)qkvb, vtb, BS * SEQ, F3, EMB, F3 / 128);

    // attn: 32 qb x 32 bh = 1024 blocks
    attn_kernel<<<dim3(1024), 256, 0, stream>>>(qkvb, vtb, aob);

    // GEMM2: [4096,1024] @ [1024,1024]^T
    gemm_bt<false><<<dim3(256), 256, 0, stream>>>(aob, woutb, (void*)out, nullptr, BS * SEQ, EMB, EMB, EMB / 128);
}

// Round 12
// 180.371 us; speedup vs baseline: 1.8156x; 1.0011x over previous
//
#include <hip/hip_runtime.h>
#include <stdint.h>

#define SEQ 2048
#define BS 2
#define EMB 1024
#define NH 16
#define HD 64
#define F3 3072

using f32x4 = __attribute__((ext_vector_type(4))) float;
using bf16x8 = __attribute__((ext_vector_type(8))) short;

__device__ __forceinline__ unsigned short f2bf(float f) {
    union { float f; uint32_t u; } v; v.f = f;
    uint32_t u = v.u;
    u = u + 0x7FFFu + ((u >> 16) & 1u);   // RNE
    return (unsigned short)(u >> 16);
}

// v_cvt_pk_bf16_f32: dst = {hi16=cvt(b), lo16=cvt(a)}
__device__ __forceinline__ uint32_t pk_bf16(float a, float b) {
    uint32_t r;
    asm("v_cvt_pk_bf16_f32 %0, %1, %2" : "=v"(r) : "v"(a), "v"(b));
    return r;
}

#define GLOAD_LDS16(g, l) \
    __builtin_amdgcn_global_load_lds((const __attribute__((address_space(1))) void*)(g), \
                                     (__attribute__((address_space(3))) void*)(l), 16, 0, 0)

// ---------------- fused fp32 -> bf16 conversion (x | Win | Wout -> contiguous ws) ----------------
__global__ void cvt_kernel(const float* __restrict__ x, const float* __restrict__ win,
                           const float* __restrict__ wout, unsigned short* __restrict__ outb) {
    const int NX4 = BS * SEQ * EMB / 4;            // 1048576
    const int NW4 = NX4 + F3 * EMB / 4;            // 1835008
    int i = blockIdx.x * blockDim.x + threadIdx.x;
    const float* src;
    int j;
    if (i < NX4)       { src = x;    j = i; }
    else if (i < NW4)  { src = win;  j = i - NX4; }
    else               { src = wout; j = i - NW4; }
    f32x4 v = reinterpret_cast<const f32x4*>(src)[j];
    uint2 o;
    o.x = pk_bf16(v.x, v.y);
    o.y = pk_bf16(v.z, v.w);
    reinterpret_cast<uint2*>(outb)[i] = o;
}

// ---------------- GEMM: C[M,N] = A[M,K] @ B[N,K]^T ----------------
// 2-phase double-buffered LDS. QKV mode: V-third columns written TRANSPOSED
// into vT[b][h][d][s].
template <bool QKV>
__global__ __launch_bounds__(256) void gemm_bt(
    const unsigned short* __restrict__ A,
    const unsigned short* __restrict__ B,
    void* __restrict__ Cv,
    unsigned short* __restrict__ vT,
    int M, int N, int K, int nbx)
{
    __shared__ unsigned short As[2][128 * 32];
    __shared__ unsigned short Bs[2][128 * 32];
    const int tid  = threadIdx.x;
    const int wave = tid >> 6, lane = tid & 63;
    const int wr = wave >> 1, wc = wave & 1;

    const int nwg = gridDim.x;
    const int sw = (blockIdx.x & 7) * (nwg >> 3) + (blockIdx.x >> 3);
    const int bx = sw % nbx, by = sw / nbx;
    const int row0 = by * 128, col0 = bx * 128;

    f32x4 acc[4][4] = {};

    const int srow = wave * 16 + (lane >> 2);
    const int scol = (lane & 3) * 8;

    const unsigned short* gA = A + (size_t)(row0 + srow) * K + scol;
    const unsigned short* gB = B + (size_t)(col0 + srow) * K + scol;
    const int lofs = wave * 16 * 32;

#define STAGE_G(buf, kb) do { \
    GLOAD_LDS16(gA + (kb),                   As[buf] + lofs); \
    GLOAD_LDS16(gA + (size_t)64 * K + (kb),  As[buf] + 64 * 32 + lofs); \
    GLOAD_LDS16(gB + (kb),                   Bs[buf] + lofs); \
    GLOAD_LDS16(gB + (size_t)64 * K + (kb),  Bs[buf] + 64 * 32 + lofs); } while (0)

    STAGE_G(0, 0);
    asm volatile("s_waitcnt vmcnt(0)" ::: "memory");
    __syncthreads();

    int cur = 0;
    for (int kb = 0; kb < K; kb += 32) {
        if (kb + 32 < K) STAGE_G(cur ^ 1, kb + 32);

        bf16x8 af[4], bfr[4];
#pragma unroll
        for (int mi = 0; mi < 4; mi++)
            af[mi] = *reinterpret_cast<const bf16x8*>(As[cur] + (wr * 64 + mi * 16 + (lane & 15)) * 32 + (lane >> 4) * 8);
#pragma unroll
        for (int ni = 0; ni < 4; ni++)
            bfr[ni] = *reinterpret_cast<const bf16x8*>(Bs[cur] + (wc * 64 + ni * 16 + (lane & 15)) * 32 + (lane >> 4) * 8);
#pragma unroll
        for (int mi = 0; mi < 4; mi++)
#pragma unroll
            for (int ni = 0; ni < 4; ni++)
                acc[mi][ni] = __builtin_amdgcn_mfma_f32_16x16x32_bf16(af[mi], bfr[ni], acc[mi][ni], 0, 0, 0);

        asm volatile("s_waitcnt vmcnt(0)" ::: "memory");
        __syncthreads();
        cur ^= 1;
    }
#undef STAGE_G

    if constexpr (QKV) {
        if (col0 >= 2 * EMB) {
#pragma unroll
            for (int mi = 0; mi < 4; mi++)
#pragma unroll
                for (int ni = 0; ni < 4; ni++) {
                    int vcol = col0 - 2 * EMB + wc * 64 + ni * 16 + (lane & 15);
                    int hh = vcol >> 6, dd = vcol & 63;
                    int row = row0 + wr * 64 + mi * 16 + (lane >> 4) * 4;
                    int bb = row >> 11, ss = row & 2047;
                    uint2 pk;
                    pk.x = pk_bf16(acc[mi][ni][0], acc[mi][ni][1]);
                    pk.y = pk_bf16(acc[mi][ni][2], acc[mi][ni][3]);
                    *reinterpret_cast<uint2*>(vT + (size_t)((bb * 16 + hh) * 64 + dd) * 2048 + ss) = pk;
                }
        } else {
#pragma unroll
            for (int mi = 0; mi < 4; mi++)
#pragma unroll
                for (int ni = 0; ni < 4; ni++)
#pragma unroll
                    for (int r = 0; r < 4; r++) {
                        int row = row0 + wr * 64 + mi * 16 + (lane >> 4) * 4 + r;
                        int col = col0 + wc * 64 + ni * 16 + (lane & 15);
                        ((unsigned short*)Cv)[(size_t)row * N + col] = f2bf(acc[mi][ni][r]);
                    }
        }
    } else {
#pragma unroll
        for (int mi = 0; mi < 4; mi++)
#pragma unroll
            for (int ni = 0; ni < 4; ni++)
#pragma unroll
                for (int r = 0; r < 4; r++) {
                    int row = row0 + wr * 64 + mi * 16 + (lane >> 4) * 4 + r;
                    int col = col0 + wc * 64 + ni * 16 + (lane & 15);
                    ((float*)Cv)[(size_t)row * N + col] = acc[mi][ni][r];
                }
    }
}

// ---------------- causal flash attention ----------------
// QBLK=64, 4 waves x 16 q-rows. swapped-QK^T in-reg softmax, reg-prefetch (T14),
// defer-max (T13), pre-transposed V, setprio (T5).
// Balanced mapping: per-CU 4-block work sums to exactly 66 tile-units under
// o%8->XCD, (o>>3)%32->CU, (o>>8)->slot dispatch; bh%8->XCD keeps KV L2-local.
__global__ __launch_bounds__(256) void attn_kernel(
    const unsigned short* __restrict__ qkv,
    const unsigned short* __restrict__ vT,
    unsigned short* __restrict__ ao)
{
    const int o = blockIdx.x;                 // 0..1023
    const int bh = o & 31;
    const int m_ = (o >> 5) & 7;
    const int r_ = o >> 8;                    // 0..3
    const int qb = (r_ == 0) ? m_ : (r_ == 1) ? 15 - m_ : (r_ == 2) ? 16 + m_ : 31 - m_;
    const int b = bh >> 4, h = bh & 15;
    const int tid = threadIdx.x, wave = tid >> 6, lane = tid & 63;
    const int c = lane & 15, g = lane >> 4;

    __shared__ unsigned short Ks[64 * 64];      // [kpos][d], swz (row&7)<<4
    __shared__ unsigned short Vs[64 * 64];      // [d][kpos], swz ((d&7)^(d>>3))<<4
    __shared__ unsigned short Ps[4][16 * 64];   // per-wave P [q][k], swz (row&7)<<4

    const size_t base = (size_t)b * SEQ * F3;
    const int qrow0 = qb * 64 + wave * 16;
    const float SC = 0.18033688011f;            // 0.125 * log2(e)

    bf16x8 qf[2];
#pragma unroll
    for (int sdq = 0; sdq < 2; sdq++) {
        int row = qrow0 + c;
        int d   = sdq * 32 + g * 8;
        qf[sdq] = *reinterpret_cast<const bf16x8*>(qkv + base + (size_t)row * F3 + h * HD + d);
    }

    f32x4 po[4] = {};
    float mR = -1e30f, lR = 0.f;

    const int ktiles = qb + 1;
    const int vrow = tid >> 3;           // 0..31
    const int sch  = tid & 7;

    const unsigned short* gK  = qkv + base + EMB + h * HD + sch * 8;
    const unsigned short* gVT = vT + (size_t)bh * 64 * SEQ + sch * 8;

    bf16x8 kp0 = *reinterpret_cast<const bf16x8*>(gK + (size_t)vrow * F3);
    bf16x8 kp1 = *reinterpret_cast<const bf16x8*>(gK + (size_t)(32 + vrow) * F3);
    bf16x8 vp0 = *reinterpret_cast<const bf16x8*>(gVT + (size_t)vrow * SEQ);
    bf16x8 vp1 = *reinterpret_cast<const bf16x8*>(gVT + (size_t)(32 + vrow) * SEQ);

    for (int kt_i = 0; kt_i < ktiles; kt_i++) {
        const int kbase = kt_i * 64;
        __syncthreads();
        {
            int off0 = (vrow * 128 + sch * 16) ^ ((vrow & 7) << 4);
            *reinterpret_cast<bf16x8*>((char*)Ks + off0) = kp0;
            int r1 = 32 + vrow;
            int off1 = (r1 * 128 + sch * 16) ^ ((r1 & 7) << 4);
            *reinterpret_cast<bf16x8*>((char*)Ks + off1) = kp1;
            int vo0 = (vrow * 128 + sch * 16) ^ ((((vrow & 7) ^ (vrow >> 3)) & 7) << 4);
            *reinterpret_cast<bf16x8*>((char*)Vs + vo0) = vp0;
            int vo1 = (r1 * 128 + sch * 16) ^ ((((r1 & 7) ^ (r1 >> 3)) & 7) << 4);
            *reinterpret_cast<bf16x8*>((char*)Vs + vo1) = vp1;
        }
        __syncthreads();

        if (kt_i + 1 < ktiles) {
            const int nb = kbase + 64;
            kp0 = *reinterpret_cast<const bf16x8*>(gK + (size_t)(nb + vrow) * F3);
            kp1 = *reinterpret_cast<const bf16x8*>(gK + (size_t)(nb + 32 + vrow) * F3);
            vp0 = *reinterpret_cast<const bf16x8*>(gVT + (size_t)vrow * SEQ + nb);
            vp1 = *reinterpret_cast<const bf16x8*>(gVT + (size_t)(32 + vrow) * SEQ + nb);
        }

        // S^T = K @ Q^T
        f32x4 st[4] = {};
        __builtin_amdgcn_s_setprio(1);
#pragma unroll
        for (int dstep = 0; dstep < 2; dstep++) {
            bf16x8 kf[4];
#pragma unroll
            for (int kt = 0; kt < 4; kt++) {
                int row = kt * 16 + c;
                int off = (row * 128 + dstep * 64 + g * 16) ^ ((row & 7) << 4);
                kf[kt] = *reinterpret_cast<const bf16x8*>((char*)Ks + off);
            }
#pragma unroll
            for (int kt = 0; kt < 4; kt++)
                st[kt] = __builtin_amdgcn_mfma_f32_16x16x32_bf16(kf[kt], qf[dstep], st[kt], 0, 0, 0);
        }
        __builtin_amdgcn_s_setprio(0);

        const bool needmask = (kt_i == qb);
        {
            const int q = qrow0 + c;
            float mx = -3.0e38f;
#pragma unroll
            for (int kt = 0; kt < 4; kt++)
#pragma unroll
                for (int r = 0; r < 4; r++) {
                    float v = st[kt][r];
                    if (needmask) {
                        int k = kbase + kt * 16 + g * 4 + r;
                        if (k > q) v = -3.0e38f;
                    }
                    st[kt][r] = v;
                    mx = fmaxf(mx, v);
                }
            mx = fmaxf(mx, __shfl_xor(mx, 16));
            mx = fmaxf(mx, __shfl_xor(mx, 32));

            const bool skip = __all(mx - mR <= 8.0f);   // T13
            float mn = skip ? mR : fmaxf(mR, mx);
            const float nmn = -mn * SC;
            float rs = 0.f;
#pragma unroll
            for (int kt = 0; kt < 4; kt++)
#pragma unroll
                for (int r = 0; r < 4; r++) {
                    float p = __builtin_amdgcn_exp2f(__builtin_fmaf(st[kt][r], SC, nmn));
                    st[kt][r] = p;
                    rs += p;
                }
            rs += __shfl_xor(rs, 16);
            rs += __shfl_xor(rs, 32);
            if (skip) {
                lR += rs;
            } else {
                float alpha = __builtin_amdgcn_exp2f((mR - mn) * SC);
                mR = mn;
                lR = lR * alpha + rs;
#pragma unroll
                for (int r = 0; r < 4; r++) {
                    float ar = __shfl(alpha, (g << 2) + r);
#pragma unroll
                    for (int ni = 0; ni < 4; ni++) po[ni][r] *= ar;
                }
            }
        }

        // P -> wave LDS
        unsigned short* Pw = Ps[wave];
        {
#pragma unroll
            for (int kt = 0; kt < 4; kt++) {
                uint2 pk;
                pk.x = pk_bf16(st[kt][0], st[kt][1]);
                pk.y = pk_bf16(st[kt][2], st[kt][3]);
                int off = (c * 128 + kt * 32 + g * 8) ^ ((c & 7) << 4);
                *reinterpret_cast<uint2*>((char*)Pw + off) = pk;
            }
        }

        // PV
        __builtin_amdgcn_s_setprio(1);
#pragma unroll
        for (int s2 = 0; s2 < 2; s2++) {
            bf16x8 pa, vb[4];
            {
                int off = (c * 128 + s2 * 64 + g * 16) ^ ((c & 7) << 4);
                pa = *reinterpret_cast<const bf16x8*>((char*)Pw + off);
            }
#pragma unroll
            for (int ni = 0; ni < 4; ni++) {
                int n = ni * 16 + c;
                int off = (n * 128 + s2 * 64 + g * 16) ^ ((((n & 7) ^ (n >> 3)) & 7) << 4);
                vb[ni] = *reinterpret_cast<const bf16x8*>((char*)Vs + off);
            }
#pragma unroll
            for (int ni = 0; ni < 4; ni++)
                po[ni] = __builtin_amdgcn_mfma_f32_16x16x32_bf16(pa, vb[ni], po[ni], 0, 0, 0);
        }
        __builtin_amdgcn_s_setprio(0);
    }

    // epilogue
    {
        float invl = 1.0f / lR;
#pragma unroll
        for (int r = 0; r < 4; r++) {
            float iv = __shfl(invl, (g << 2) + r);
            int row = qrow0 + g * 4 + r;
#pragma unroll
            for (int ni = 0; ni < 4; ni++) {
                int d = ni * 16 + c;
                ao[(size_t)(b * SEQ + row) * EMB + h * HD + d] = f2bf(po[ni][r] * iv);
            }
        }
    }
}

// ---------------- launch ----------------
extern "C" void kernel_launch(void* const* d_in, const int* in_sizes, int n_in,
                              void* d_out, int out_size, void* d_ws, size_t ws_size,
                              hipStream_t stream)
{
    const float* x    = (const float*)d_in[0];
    const float* Win  = (const float*)d_in[1];
    const float* Wout = (const float*)d_in[2];
    float* out = (float*)d_out;

    char* ws = (char*)d_ws;
    unsigned short* xb    = (unsigned short*)(ws);                  //  8 MB
    unsigned short* winb  = (unsigned short*)(ws + (8u  << 20));    //  6 MB
    unsigned short* woutb = (unsigned short*)(ws + (14u << 20));    //  2 MB
    unsigned short* qkvb  = (unsigned short*)(ws + (16u << 20));    // 24 MB
    unsigned short* aob   = (unsigned short*)(ws + (40u << 20));    //  8 MB
    unsigned short* vtb   = (unsigned short*)(ws + (48u << 20));    //  8 MB  V^T [b][h][d][s]

    // fused cvt: 2097152 vec4 elements = 8192 blocks
    cvt_kernel<<<dim3(8192), 256, 0, stream>>>(x, Win, Wout, xb);

    gemm_bt<true><<<dim3(768), 256, 0, stream>>>(xb, winb, (void*)qkvb, vtb, BS * SEQ, F3, EMB, F3 / 128);

    attn_kernel<<<dim3(1024), 256, 0, stream>>>(qkvb, vtb, aob);

    gemm_bt<false><<<dim3(256), 256, 0, stream>>>(aob, woutb, (void*)out, nullptr, BS * SEQ, EMB, EMB, EMB / 128);
}